// Round 21
// baseline (86.286 us; speedup 1.0000x reference)
//
#include <hip/hip_runtime.h>

typedef __bf16 bf16x8 __attribute__((ext_vector_type(8)));
typedef float  f32x4  __attribute__((ext_vector_type(4)));
typedef float  f32x16 __attribute__((ext_vector_type(16)));
typedef float  f32x2  __attribute__((ext_vector_type(2)));
typedef unsigned int uint32;
typedef unsigned int u32x2 __attribute__((ext_vector_type(2)));
typedef unsigned int u32x4 __attribute__((ext_vector_type(4)));
typedef int i32x4 __attribute__((ext_vector_type(4)));
typedef int i32x8 __attribute__((ext_vector_type(8)));
typedef long long i64;
typedef long long i64x4v __attribute__((ext_vector_type(4)));

#define MFMA16(a, b, c) __builtin_amdgcn_mfma_f32_16x16x32_bf16((a), (b), (c), 0, 0, 0)
#define MFMA32F8(a, b, c) __builtin_amdgcn_mfma_f32_32x32x16_fp8_fp8((a), (b), (c), 0, 0, 0)
// global -> LDS direct DMA, 16B per lane; dest = wave-uniform base + lane*16
#define GLL(gsrc, ldst) __builtin_amdgcn_global_load_lds( \
    (const __attribute__((address_space(1))) uint32*)(gsrc), \
    (__attribute__((address_space(3))) uint32*)(ldst), 16, 0, 0)

static constexpr int Cch = 128;   // channels
static constexpr int Nvox = 8192; // D*H*W = 8*32*32

// K=64 fp8 matmul: MX-scaled instr at 2x rate with unit scales (e8m0 127),
// or 4x pairwise 32x32x16 fp8 (bit-identical math) if builtin is absent.
__device__ inline f32x16 mx4(i32x8 a, i32x8 b, f32x16 c) {
#if __has_builtin(__builtin_amdgcn_mfma_scale_f32_32x32x64_f8f6f4)
  return __builtin_amdgcn_mfma_scale_f32_32x32x64_f8f6f4(
      a, b, c, 0 /*cbsz: fp8*/, 0 /*blgp: fp8*/,
      0, 0x7F7F7F7Fu, 0, 0x7F7F7F7Fu /*unit scales*/);
#else
  i64x4v av = __builtin_bit_cast(i64x4v, a);
  i64x4v bv = __builtin_bit_cast(i64x4v, b);
  c = MFMA32F8(av[0], bv[0], c);
  c = MFMA32F8(av[1], bv[1], c);
  c = MFMA32F8(av[2], bv[2], c);
  c = MFMA32F8(av[3], bv[3], c);
  return c;
#endif
}

__device__ inline unsigned int pkbf(float x, float y) {
  unsigned short ux = __builtin_bit_cast(unsigned short, (__bf16)x);
  unsigned short uy = __builtin_bit_cast(unsigned short, (__bf16)y);
  return (unsigned int)ux | ((unsigned int)uy << 16);
}

// pack 4 f32 -> 4 fp8 e4m3 bytes (OCP, HW cvt)
__device__ inline unsigned int pk4fp8(float a, float b, float c, float d) {
  int w = 0;
  w = __builtin_amdgcn_cvt_pk_fp8_f32(a, b, w, false);
  w = __builtin_amdgcn_cvt_pk_fp8_f32(c, d, w, true);
  return (unsigned int)w;
}
__device__ inline unsigned char fp8b(float x) {
  return (unsigned char)(__builtin_amdgcn_cvt_pk_fp8_f32(x, x, 0, false) & 0xff);
}

// exchange halves: x' = {x[0:31], y[0:31]}, y' = {x[32:63], y[32:63]}
__device__ inline void lane32_swap(unsigned int& x, unsigned int& y) {
#if __has_builtin(__builtin_amdgcn_permlane32_swap)
  auto r = __builtin_amdgcn_permlane32_swap(x, y, false, false);
  x = r[0]; y = r[1];
#else
  unsigned int sx = (unsigned int)__shfl_xor((int)x, 32);
  unsigned int sy = (unsigned int)__shfl_xor((int)y, 32);
  bool lo = ((threadIdx.x & 63) < 32);
  unsigned int nx = lo ? x : sy;
  unsigned int ny = lo ? sx : y;
  x = nx; y = ny;
#endif
}
__device__ inline float red32_sum(float v) {
  unsigned int a = __builtin_bit_cast(unsigned int, v), b = a;
  lane32_swap(a, b);
  return __builtin_bit_cast(float, a) + __builtin_bit_cast(float, b);
}

// ---------------- K1: GroupNorm partial sums + weight cast: 256 blocks -------
__global__ __launch_bounds__(256) void gn_part_k(const float* __restrict__ x,
                                                 f32x2* __restrict__ part,
                                                 const float* __restrict__ wq,
                                                 const float* __restrict__ wp,
                                                 __bf16* __restrict__ wqb,
                                                 __bf16* __restrict__ wpb) {
  // fused conv_w: 256*256 = 65536 = 49152 (wq) + 16384 (wp), one elem/thread
  int wi = blockIdx.x * 256 + threadIdx.x;
  if (wi < 49152) wqb[wi] = (__bf16)wq[wi];
  else wpb[wi - 49152] = (__bf16)wp[wi - 49152];

  int bg = blockIdx.x >> 4, pt = blockIdx.x & 15;
  const f32x4* xb = (const f32x4*)(x + (size_t)bg * 131072 + (size_t)pt * 8192);
  float s = 0.f, ss = 0.f;
  for (int i = threadIdx.x; i < 2048; i += 256) {
    f32x4 v = xb[i];
    s += (v.x + v.y) + (v.z + v.w);
    ss += (v.x * v.x + v.y * v.y) + (v.z * v.z + v.w * v.w);
  }
#pragma unroll
  for (int off = 32; off; off >>= 1) {
    s  += __shfl_down(s, off);
    ss += __shfl_down(ss, off);
  }
  __shared__ float rb[4], rbss[4];
  if ((threadIdx.x & 63) == 0) { rb[threadIdx.x >> 6] = s; rbss[threadIdx.x >> 6] = ss; }
  __syncthreads();
  if (threadIdx.x == 0) {
    f32x2 o; o.x = rb[0] + rb[1] + rb[2] + rb[3];
    o.y = rbss[0] + rbss[1] + rbss[2] + rbss[3];
    part[blockIdx.x] = o;
  }
}

// ---------------- K2: GN finish (fused) + normalize + transpose --------------
__global__ __launch_bounds__(256) void gn_apply_k(const float* __restrict__ x,
                                                  const float* __restrict__ gamma,
                                                  const float* __restrict__ beta,
                                                  const f32x2* __restrict__ part,
                                                  __bf16* __restrict__ xn) {
  __shared__ __bf16 t[64][136];
  __shared__ float sm_mean[16], sm_rstd[16];
  int tid = threadIdx.x;
  {
    f32x2 v = part[tid];
    float s = v.x, ss = v.y;
#pragma unroll
    for (int off = 1; off < 16; off <<= 1) {
      s += __shfl_xor(s, off);
      ss += __shfl_xor(ss, off);
    }
    if ((tid & 15) == 0) {
      int bg = tid >> 4;
      const float invn = 1.f / 131072.f;
      float mean = s * invn;
      float var = ss * invn - mean * mean;
      sm_mean[bg] = mean;
      sm_rstd[bg] = rsqrtf(var + 1e-5f);
    }
  }
  __syncthreads();
  int b = blockIdx.x >> 7;
  int n0 = (blockIdx.x & 127) << 6;
  const float* xb = x + (size_t)b * Cch * Nvox;
  for (int i = threadIdx.x; i < 128 * 64; i += 256) {
    int c = i >> 6, nl = i & 63;
    int g = c >> 4;
    float mean = sm_mean[b * 8 + g];
    float rstd = sm_rstd[b * 8 + g];
    float v = xb[(size_t)c * Nvox + n0 + nl];
    t[nl][c] = (__bf16)((v - mean) * rstd * gamma[c] + beta[c]);
  }
  __syncthreads();
  __bf16* outb = xn + (size_t)b * Nvox * Cch;
  for (int i = threadIdx.x; i < 64 * 16; i += 256) {
    int row = i >> 4, ch = (i & 15) << 3;
    *reinterpret_cast<bf16x8*>(&outb[(size_t)(n0 + row) * Cch + ch]) =
        *reinterpret_cast<const bf16x8*>(&t[row][ch]);
  }
}

// ---------------- K3: QKV GEMM (n-tile resident) ------------------------------
// 256 blocks = b(2) x n0(128). The 64n x 128c xn tile is staged ONCE in LDS
// and all 6 o-tiles computed against it. V via LDS transpose -> coalesced.
__global__ __launch_bounds__(256) void qkv_k(const __bf16* __restrict__ xn,
                                             const __bf16* __restrict__ wq,
                                             const float* __restrict__ b_qkv,
                                             unsigned char* __restrict__ q8,
                                             unsigned char* __restrict__ k8,
                                             unsigned char* __restrict__ v8t) {
  __shared__ __bf16 xt[64][136];         // 17.0 KB, padded rows
  __shared__ unsigned char vtl[64][64];  // 4 KB transpose tile
  int id = blockIdx.x;
  int b = id >> 7;
  int n0 = (id & 127) * 64;
  int w = threadIdx.x >> 6, l = threadIdx.x & 63;
  int lr = l & 15, lh = l >> 4;
  const float k2 = 0.08838834764831845f * 1.4426950408889634f;

  // stage xn tile: 64 rows x 128 c bf16
  const __bf16* xb = xn + ((size_t)b * Nvox + n0) * Cch;
  for (int i = threadIdx.x; i < 64 * 16; i += 256) {
    int row = i >> 4, ch = (i & 15) << 3;
    *reinterpret_cast<bf16x8*>(&xt[row][ch]) =
        *reinterpret_cast<const bf16x8*>(&xb[(size_t)row * Cch + ch]);
  }
  __syncthreads();

#pragma unroll
  for (int ot = 0; ot < 6; ++ot) {       // uniform o-tile loop
    int o0b = ot * 64;
    int ow = o0b + w * 16;
    bf16x8 a[4];
#pragma unroll
    for (int kc = 0; kc < 4; kc++)
      a[kc] = *reinterpret_cast<const bf16x8*>(
          &wq[(size_t)(ow + lr) * 128 + kc * 32 + lh * 8]);

#pragma unroll
    for (int ns = 0; ns < 4; ns++) {
      f32x4 acc = {0.f, 0.f, 0.f, 0.f};
#pragma unroll
      for (int kc = 0; kc < 4; kc++) {
        bf16x8 bf = *reinterpret_cast<const bf16x8*>(
            &xt[ns * 16 + lr][kc * 32 + lh * 8]);
        acc = MFMA16(a[kc], bf, acc);
      }
      int o0 = ow + lh * 4;
      int n = n0 + ns * 16 + lr;
      float f0 = acc[0] + b_qkv[o0 + 0];
      float f1 = acc[1] + b_qkv[o0 + 1];
      float f2 = acc[2] + b_qkv[o0 + 2];
      float f3 = acc[3] + b_qkv[o0 + 3];
      if (ot < 2) {
        *reinterpret_cast<unsigned int*>(
            q8 + ((size_t)b * Nvox + n) * 128 + o0) =
            pk4fp8(f0 * k2, f1 * k2, f2 * k2, f3 * k2);
      } else if (ot < 4) {
        *reinterpret_cast<unsigned int*>(
            k8 + ((size_t)b * Nvox + n) * 128 + (o0 - 128)) =
            pk4fp8(f0, f1, f2, f3);
      } else {
        // V: stage into LDS transpose tile with the n-permutation applied
        int crel = w * 16 + lh * 4;      // 0..63 within this 64-c tile
        int kk = ns * 16 + lr;           // n & 63
        int r4 = kk & 15;
        int hh = (r4 >> 2) & 1;
        int jj = (r4 & 3) + (((r4 >> 3) & 1) << 2);
        int m = ((kk >> 5) << 5) + (hh << 4) + (((kk >> 4) & 1) << 3) + jj;
        vtl[crel + 0][m] = fp8b(f0);
        vtl[crel + 1][m] = fp8b(f1);
        vtl[crel + 2][m] = fp8b(f2);
        vtl[crel + 3][m] = fp8b(f3);
      }
    }
    if (ot >= 4) {                       // uniform branch: V write-out
      __syncthreads();                   // vtl stores visible to all
      int cbase = (ot - 4) * 64;
      int row = threadIdx.x >> 2, seg = threadIdx.x & 3;
      *reinterpret_cast<u32x4*>(
          v8t + ((size_t)b * Cch + cbase + row) * Nvox + n0 + seg * 16) =
          *reinterpret_cast<const u32x4*>(&vtl[row][seg * 16]);
      __syncthreads();                   // reads done before ot=5 restores vtl
    }
  }
}

// ---------------- K4: flash attention v19 (cross-iter MFMA pipeline) ---------
// v16 base (512 blocks = qgrp(64) x b(2) x kq(4); 4 warps, q=32/warp,
// KVBLK=64, NT=32, fp8 K=64 MFMA, max-free softmax, in-lane P pack).
// NEW: QK(t) and PV(t-1) fused into ONE MFMA cluster (8 independent mx4) —
// removes the two MFMA-latency stalls of the serialized QK->SM->PV chain
// (r19 showed barriers are NOT the wall; the intra-wave chain is).
// Requires V(t-1) to survive stage(t+1): TRIPLE buffer (3x16KB = 48KB,
// still 2 blocks/CU at 96KB). pb carried across iters (+8 VGPR, ~160 total).
// Safety: all PV(t-1) LDS reads complete before the iter-(t+1) barrier
// (program order + lgkm drain); stage(t+2) into that buffer is issued only
// after that barrier -> no overwrite race.
__global__ __launch_bounds__(256, 2) void attn_k(const unsigned char* __restrict__ q,
                                                 const unsigned char* __restrict__ kk,
                                                 const unsigned char* __restrict__ vt,
                                                 __bf16* __restrict__ po0,
                                                 __bf16* __restrict__ po1,
                                                 __bf16* __restrict__ po2,
                                                 __bf16* __restrict__ po3,
                                                 f32x2* __restrict__ ml) {
  extern __shared__ char smem[];   // 48KB: 3 x [K 8K | V 8K]
  const int bi = blockIdx.x;
  const int kq = bi & 3;
  const int b = (bi >> 2) & 1;
  const int qgrp = bi >> 3;            // 0..63
  const int w = threadIdx.x >> 6;      // 0..3 = q-tile (32 q each)
  const int l = threadIdx.x & 63;
  const int l31 = l & 31, h = l >> 5;
  const int swl16 = (l31 & 15) << 4;   // read swizzle for 256B rows

  const char* kbase = (const char*)kk + ((size_t)b * 8192 + (size_t)kq * 2048) * 128;
  const char* vbase = (const char*)vt + (size_t)b * 1048576 + (size_t)kq * 2048;

  // Q B-fragments (fp8, pre-scaled by k2): col q = l31
  const unsigned char* qrow = q +
      ((size_t)b * 8192 + (size_t)qgrp * 128 + (size_t)w * 32 + l31) * 128 + h * 32;
  i32x8 qa8[2];
#pragma unroll
  for (int dc = 0; dc < 2; dc++) {
    i32x4 q0 = *reinterpret_cast<const i32x4*>(qrow + dc * 64);
    i32x4 q1 = *reinterpret_cast<const i32x4*>(qrow + dc * 64 + 16);
    qa8[dc] = __builtin_shufflevector(q0, q1, 0, 1, 2, 3, 4, 5, 6, 7);
  }

  f32x16 O[4];
#pragma unroll
  for (int cb = 0; cb < 4; cb++)
#pragma unroll
    for (int r = 0; r < 16; r++) O[cb][r] = 0.f;
  float s0 = 0.f, s1 = 0.f, s2 = 0.f, s3 = 0.f;  // persistent P-sum partials
  i32x8 pbp = {};                                // P pack of previous tile

  // stage one 64-row K/V fp8 tile pair (16KB): warps 0-1 K, 2-3 V; 4KB each.
  auto stage = [&](int t, int bs) {
    if (w < 2) {
      const char* kt = kbase + (size_t)t * 64 * 128;   // K rows 128B (fp8)
      char* dst = smem + bs * 16384;
#pragma unroll
      for (int it = 0; it < 4; ++it) {
        int ob = (w * 4 + it) * 1024;
        int o = ob + l * 16;
        int row = o >> 8;
        int lcol = (o & 255) ^ ((row & 15) << 4);
        int ksel = lcol >> 7, c = lcol & 127;
        GLL(kt + (size_t)(ksel * 32 + row) * 128 + c, dst + ob);
      }
    } else {
      const char* vtile = vbase + (size_t)t * 64;      // V^T c-rows 8192B (fp8)
      char* dst = smem + bs * 16384 + 8192;
#pragma unroll
      for (int it = 0; it < 4; ++it) {
        int ob = ((w - 2) * 4 + it) * 1024;
        int o = ob + l * 16;
        int row = o >> 8;
        int lcol = (o & 255) ^ ((row & 15) << 4);
        int cs = lcol >> 6, k16 = lcol & 63;
        GLL(vtile + (size_t)(cs * 32 + row) * 8192 + k16, dst + ob);
      }
    }
  };

  stage(0, 0);
  int prv = 2, cur = 0, nxt = 1;
  const int NT = 32;

  for (int t = 0; t < NT; ++t) {
    // explicit drain: this wave's DMA + LDS reads complete before barrier
    asm volatile("s_waitcnt vmcnt(0) lgkmcnt(0)" ::: "memory");
    __builtin_amdgcn_sched_barrier(0);
    __syncthreads();                   // buf[cur] staged for ALL waves
    if (t + 1 < NT) stage(t + 1, nxt);

    const char* Kb = smem + cur * 16384;
    const char* Vbp = smem + prv * 16384 + 8192;  // V of tile t-1

    // ---- fused MFMA cluster: QK(t) + PV(t-1) (8 independent mx4) ----------
    f32x16 St[2];
#pragma unroll
    for (int ks = 0; ks < 2; ks++)
#pragma unroll
      for (int r = 0; r < 16; r++) St[ks][r] = 0.f;
    __builtin_amdgcn_s_setprio(1);
#pragma unroll
    for (int ks = 0; ks < 2; ks++) {
#pragma unroll
      for (int dc = 0; dc < 2; dc++) {
        int base = ks * 128 + dc * 64 + h * 32;
        i32x4 k0 = *reinterpret_cast<const i32x4*>(
            Kb + (size_t)l31 * 256 + (base ^ swl16));
        i32x4 k1 = *reinterpret_cast<const i32x4*>(
            Kb + (size_t)l31 * 256 + ((base + 16) ^ swl16));
        St[ks] = mx4(__builtin_shufflevector(k0, k1, 0, 1, 2, 3, 4, 5, 6, 7),
                     qa8[dc], St[ks]);
      }
    }
    if (t > 0) {                       // PV of previous tile (uniform branch)
#pragma unroll
      for (int cb = 0; cb < 4; cb++) {
        int vb0 = cb * 64 + h * 16;
        i32x4 v0 = *reinterpret_cast<const i32x4*>(
            Vbp + (size_t)l31 * 256 + (vb0 ^ swl16));
        i32x4 v1 = *reinterpret_cast<const i32x4*>(
            Vbp + (size_t)l31 * 256 + ((vb0 + 32) ^ swl16));
        O[cb] = mx4(__builtin_shufflevector(v0, v1, 0, 1, 2, 3, 4, 5, 6, 7),
                    pbp, O[cb]);
      }
    }
    __builtin_amdgcn_s_setprio(0);

    // ---- VALU cluster: max-free softmax + sums + fp8 pack -> pbp ----------
#pragma unroll
    for (int ks = 0; ks < 2; ks++)
#pragma unroll
      for (int r = 0; r < 16; r++)
        St[ks][r] = __builtin_amdgcn_exp2f(St[ks][r]);
#pragma unroll
    for (int ks = 0; ks < 2; ks++)
#pragma unroll
      for (int r = 0; r < 16; r += 4) {
        s0 += St[ks][r + 0]; s1 += St[ks][r + 1];
        s2 += St[ks][r + 2]; s3 += St[ks][r + 3];
      }
#pragma unroll
    for (int ks = 0; ks < 2; ks++) {
      pbp[ks * 4 + 0] = (int)pk4fp8(St[ks][0],  St[ks][1],  St[ks][2],  St[ks][3]);
      pbp[ks * 4 + 1] = (int)pk4fp8(St[ks][4],  St[ks][5],  St[ks][6],  St[ks][7]);
      pbp[ks * 4 + 2] = (int)pk4fp8(St[ks][8],  St[ks][9],  St[ks][10], St[ks][11]);
      pbp[ks * 4 + 3] = (int)pk4fp8(St[ks][12], St[ks][13], St[ks][14], St[ks][15]);
    }

    int op = prv; prv = cur; cur = nxt; nxt = op;  // rotate triple buffer
  }

  // ---- epilogue: drain PV of the last tile (buffer prv after rotation) ----
  {
    const char* Vbp = smem + prv * 16384 + 8192;
    __builtin_amdgcn_s_setprio(1);
#pragma unroll
    for (int cb = 0; cb < 4; cb++) {
      int vb0 = cb * 64 + h * 16;
      i32x4 v0 = *reinterpret_cast<const i32x4*>(
          Vbp + (size_t)l31 * 256 + (vb0 ^ swl16));
      i32x4 v1 = *reinterpret_cast<const i32x4*>(
          Vbp + (size_t)l31 * 256 + ((vb0 + 32) ^ swl16));
      O[cb] = mx4(__builtin_shufflevector(v0, v1, 0, 1, 2, 3, 4, 5, 6, 7),
                  pbp, O[cb]);
    }
    __builtin_amdgcn_s_setprio(0);
  }

  // ---- write partial O^T (bf16) + (m=0, l) ---------------------------------
  float lsum = red32_sum((s0 + s1) + (s2 + s3));
  __bf16* po = (kq == 0) ? po0 : (kq == 1) ? po1 : (kq == 2) ? po2 : po3;
  int qg = b * 8192 + qgrp * 128 + w * 32 + l31;
#pragma unroll
  for (int cb = 0; cb < 4; cb++) {
#pragma unroll
    for (int rq = 0; rq < 4; rq++) {
      int c = cb * 32 + rq * 8 + h * 4;
      u32x2 wv;
      wv[0] = pkbf(O[cb][rq * 4 + 0], O[cb][rq * 4 + 1]);
      wv[1] = pkbf(O[cb][rq * 4 + 2], O[cb][rq * 4 + 3]);
      *reinterpret_cast<u32x2*>((char*)po + ((size_t)qg * 128 + c) * 2) = wv;
    }
  }
  if (l < 32) {
    f32x2 v; v.x = 0.f; v.y = lsum;
    ml[(size_t)kq * 16384 + qg] = v;
  }
}

// ---------------- K5: proj GEMM + fused 4-way merge + bias + residual --------
__global__ __launch_bounds__(256) void proj_k(const __bf16* __restrict__ po0,
                                              const __bf16* __restrict__ po1,
                                              const __bf16* __restrict__ po2,
                                              const __bf16* __restrict__ po3,
                                              const f32x2* __restrict__ ml,
                                              const __bf16* __restrict__ wp,
                                              const float* __restrict__ b_proj,
                                              const float* __restrict__ x,
                                              float* __restrict__ out) {
  int id = blockIdx.x;            // 2 * 2 * 128
  int b = id >> 8;
  int co0 = ((id >> 7) & 1) * 64;
  int n0 = (id & 127) * 64;
  int w = threadIdx.x >> 6, l = threadIdx.x & 63;
  int lr = l & 15, lh = l >> 4;
  int cow = co0 + w * 16;

  bf16x8 a[4];
#pragma unroll
  for (int kc = 0; kc < 4; kc++)
    a[kc] = *reinterpret_cast<const bf16x8*>(&wp[(size_t)(cow + lr) * 128 + kc * 32 + lh * 8]);

#pragma unroll
  for (int ns = 0; ns < 4; ns++) {
    int n = n0 + ns * 16 + lr;
    int qg = b * 8192 + n;
    // per-lane 4-way merge coefficients (m == 0 for all partials)
    f32x2 a0 = ml[qg], a1 = ml[16384 + qg], a2 = ml[32768 + qg], a3 = ml[49152 + qg];
    float M = fmaxf(fmaxf(a0.x, a1.x), fmaxf(a2.x, a3.x));
    float e0 = __builtin_amdgcn_exp2f(a0.x - M);
    float e1 = __builtin_amdgcn_exp2f(a1.x - M);
    float e2 = __builtin_amdgcn_exp2f(a2.x - M);
    float e3 = __builtin_amdgcn_exp2f(a3.x - M);
    float invL = 1.f / (e0 * a0.y + e1 * a1.y + e2 * a2.y + e3 * a3.y);
    float c0f = e0 * invL, c1f = e1 * invL, c2f = e2 * invL, c3f = e3 * invL;

    f32x4 acc = {0.f, 0.f, 0.f, 0.f};
#pragma unroll
    for (int kc = 0; kc < 4; kc++) {
      size_t off = (size_t)qg * 128 + kc * 32 + lh * 8;
      bf16x8 v0 = *reinterpret_cast<const bf16x8*>(&po0[off]);
      bf16x8 v1 = *reinterpret_cast<const bf16x8*>(&po1[off]);
      bf16x8 v2 = *reinterpret_cast<const bf16x8*>(&po2[off]);
      bf16x8 v3 = *reinterpret_cast<const bf16x8*>(&po3[off]);
      bf16x8 hv;
#pragma unroll
      for (int i = 0; i < 8; i++)
        hv[i] = (__bf16)(c0f * (float)v0[i] + c1f * (float)v1[i] +
                         c2f * (float)v2[i] + c3f * (float)v3[i]);
      acc = MFMA16(a[kc], hv, acc);
    }
#pragma unroll
    for (int r2 = 0; r2 < 4; r2++) {
      int co = cow + lh * 4 + r2;
      size_t idx = ((size_t)b * Cch + co) * Nvox + n;
      out[idx] = x[idx] + b_proj[co] + acc[r2];
    }
  }
}

extern "C" void kernel_launch(void* const* d_in, const int* in_sizes, int n_in,
                              void* d_out, int out_size, void* d_ws, size_t ws_size,
                              hipStream_t stream) {
  const float* x      = (const float*)d_in[0];
  const float* gamma  = (const float*)d_in[1];
  const float* beta   = (const float*)d_in[2];
  const float* w_qkv  = (const float*)d_in[3];
  const float* b_qkv  = (const float*)d_in[4];
  const float* w_proj = (const float*)d_in[5];
  const float* b_proj = (const float*)d_in[6];
  float* out = (float*)d_out;

  char* ws = (char*)d_ws;
  f32x2*  part  = (f32x2*)(ws + 256);              // 2 KB
  __bf16* wq_b  = (__bf16*)(ws + 4096);            // 98304 B
  __bf16* wp_b  = (__bf16*)(ws + 4096 + 98304);    // 32768 B
  size_t base = 135168;
  const size_t SZ = (size_t)2 * Nvox * Cch * sizeof(__bf16); // 4 MiB
  __bf16* xn  = (__bf16*)(ws + base + 0 * SZ);     // reused as po1
  unsigned char* q8  = (unsigned char*)(ws + base + 1 * SZ);  // 2 MB used
  unsigned char* k8  = (unsigned char*)(ws + base + 2 * SZ);  // 2 MB used
  unsigned char* v8t = (unsigned char*)(ws + base + 3 * SZ);  // 2 MB used
  __bf16* hw  = (__bf16*)(ws + base + 4 * SZ);     // po0
  f32x2*  ml  = (f32x2*)(ws + base + 5 * SZ);      // 512 KB
  __bf16* po2 = (__bf16*)(ws + base + 5 * SZ + 524288);
  __bf16* po3 = (__bf16*)(ws + base + 5 * SZ + 524288 + SZ);
  // total ws use: ~30 MB

  (void)hipFuncSetAttribute((const void*)attn_k,
                            hipFuncAttributeMaxDynamicSharedMemorySize, 49152);

  gn_part_k<<<256, 256, 0, stream>>>(x, part, w_qkv, w_proj, wq_b, wp_b);
  gn_apply_k<<<256, 256, 0, stream>>>(x, gamma, beta, part, xn);
  qkv_k<<<256, 256, 0, stream>>>(xn, wq_b, b_qkv, q8, k8, v8t);
  attn_k<<<512, 256, 49152, stream>>>(q8, k8, v8t, hw, xn, po2, po3, ml);
  proj_k<<<512, 256, 0, stream>>>(hw, xn, po2, po3, ml, wp_b, b_proj, x, out);
}

// Round 22
// 85.973 us; speedup vs baseline: 1.0036x; 1.0036x over previous
//
#include <hip/hip_runtime.h>

typedef __bf16 bf16x8 __attribute__((ext_vector_type(8)));
typedef float  f32x4  __attribute__((ext_vector_type(4)));
typedef float  f32x16 __attribute__((ext_vector_type(16)));
typedef float  f32x2  __attribute__((ext_vector_type(2)));
typedef unsigned int uint32;
typedef unsigned int u32x2 __attribute__((ext_vector_type(2)));
typedef unsigned int u32x4 __attribute__((ext_vector_type(4)));
typedef int i32x4 __attribute__((ext_vector_type(4)));
typedef int i32x8 __attribute__((ext_vector_type(8)));
typedef long long i64;
typedef long long i64x4v __attribute__((ext_vector_type(4)));

#define MFMA16(a, b, c) __builtin_amdgcn_mfma_f32_16x16x32_bf16((a), (b), (c), 0, 0, 0)
#define MFMA32F8(a, b, c) __builtin_amdgcn_mfma_f32_32x32x16_fp8_fp8((a), (b), (c), 0, 0, 0)
// global -> LDS direct DMA, 16B per lane; dest = wave-uniform base + lane*16
#define GLL(gsrc, ldst) __builtin_amdgcn_global_load_lds( \
    (const __attribute__((address_space(1))) uint32*)(gsrc), \
    (__attribute__((address_space(3))) uint32*)(ldst), 16, 0, 0)

static constexpr int Cch = 128;   // channels
static constexpr int Nvox = 8192; // D*H*W = 8*32*32

// K=64 fp8 matmul: MX-scaled instr at 2x rate with unit scales (e8m0 127),
// or 4x pairwise 32x32x16 fp8 (bit-identical math) if builtin is absent.
__device__ inline f32x16 mx4(i32x8 a, i32x8 b, f32x16 c) {
#if __has_builtin(__builtin_amdgcn_mfma_scale_f32_32x32x64_f8f6f4)
  return __builtin_amdgcn_mfma_scale_f32_32x32x64_f8f6f4(
      a, b, c, 0 /*cbsz: fp8*/, 0 /*blgp: fp8*/,
      0, 0x7F7F7F7Fu, 0, 0x7F7F7F7Fu /*unit scales*/);
#else
  i64x4v av = __builtin_bit_cast(i64x4v, a);
  i64x4v bv = __builtin_bit_cast(i64x4v, b);
  c = MFMA32F8(av[0], bv[0], c);
  c = MFMA32F8(av[1], bv[1], c);
  c = MFMA32F8(av[2], bv[2], c);
  c = MFMA32F8(av[3], bv[3], c);
  return c;
#endif
}

__device__ inline unsigned int pkbf(float x, float y) {
  unsigned short ux = __builtin_bit_cast(unsigned short, (__bf16)x);
  unsigned short uy = __builtin_bit_cast(unsigned short, (__bf16)y);
  return (unsigned int)ux | ((unsigned int)uy << 16);
}

// pack 4 f32 -> 4 fp8 e4m3 bytes (OCP, HW cvt)
__device__ inline unsigned int pk4fp8(float a, float b, float c, float d) {
  int w = 0;
  w = __builtin_amdgcn_cvt_pk_fp8_f32(a, b, w, false);
  w = __builtin_amdgcn_cvt_pk_fp8_f32(c, d, w, true);
  return (unsigned int)w;
}
__device__ inline unsigned char fp8b(float x) {
  return (unsigned char)(__builtin_amdgcn_cvt_pk_fp8_f32(x, x, 0, false) & 0xff);
}

// exchange halves: x' = {x[0:31], y[0:31]}, y' = {x[32:63], y[32:63]}
__device__ inline void lane32_swap(unsigned int& x, unsigned int& y) {
#if __has_builtin(__builtin_amdgcn_permlane32_swap)
  auto r = __builtin_amdgcn_permlane32_swap(x, y, false, false);
  x = r[0]; y = r[1];
#else
  unsigned int sx = (unsigned int)__shfl_xor((int)x, 32);
  unsigned int sy = (unsigned int)__shfl_xor((int)y, 32);
  bool lo = ((threadIdx.x & 63) < 32);
  unsigned int nx = lo ? x : sy;
  unsigned int ny = lo ? sx : y;
  x = nx; y = ny;
#endif
}
__device__ inline float red32_sum(float v) {
  unsigned int a = __builtin_bit_cast(unsigned int, v), b = a;
  lane32_swap(a, b);
  return __builtin_bit_cast(float, a) + __builtin_bit_cast(float, b);
}

// ---------------- K1: GroupNorm partial sums + weight cast: 256 blocks -------
__global__ __launch_bounds__(256) void gn_part_k(const float* __restrict__ x,
                                                 f32x2* __restrict__ part,
                                                 const float* __restrict__ wq,
                                                 const float* __restrict__ wp,
                                                 __bf16* __restrict__ wqb,
                                                 __bf16* __restrict__ wpb) {
  // fused conv_w: 256*256 = 65536 = 49152 (wq) + 16384 (wp), one elem/thread
  int wi = blockIdx.x * 256 + threadIdx.x;
  if (wi < 49152) wqb[wi] = (__bf16)wq[wi];
  else wpb[wi - 49152] = (__bf16)wp[wi - 49152];

  int bg = blockIdx.x >> 4, pt = blockIdx.x & 15;
  const f32x4* xb = (const f32x4*)(x + (size_t)bg * 131072 + (size_t)pt * 8192);
  float s = 0.f, ss = 0.f;
  for (int i = threadIdx.x; i < 2048; i += 256) {
    f32x4 v = xb[i];
    s += (v.x + v.y) + (v.z + v.w);
    ss += (v.x * v.x + v.y * v.y) + (v.z * v.z + v.w * v.w);
  }
#pragma unroll
  for (int off = 32; off; off >>= 1) {
    s  += __shfl_down(s, off);
    ss += __shfl_down(ss, off);
  }
  __shared__ float rb[4], rbss[4];
  if ((threadIdx.x & 63) == 0) { rb[threadIdx.x >> 6] = s; rbss[threadIdx.x >> 6] = ss; }
  __syncthreads();
  if (threadIdx.x == 0) {
    f32x2 o; o.x = rb[0] + rb[1] + rb[2] + rb[3];
    o.y = rbss[0] + rbss[1] + rbss[2] + rbss[3];
    part[blockIdx.x] = o;
  }
}

// ---------------- K2: GN finish (fused) + normalize + transpose --------------
__global__ __launch_bounds__(256) void gn_apply_k(const float* __restrict__ x,
                                                  const float* __restrict__ gamma,
                                                  const float* __restrict__ beta,
                                                  const f32x2* __restrict__ part,
                                                  __bf16* __restrict__ xn) {
  __shared__ __bf16 t[64][136];
  __shared__ float sm_mean[16], sm_rstd[16];
  int tid = threadIdx.x;
  {
    f32x2 v = part[tid];
    float s = v.x, ss = v.y;
#pragma unroll
    for (int off = 1; off < 16; off <<= 1) {
      s += __shfl_xor(s, off);
      ss += __shfl_xor(ss, off);
    }
    if ((tid & 15) == 0) {
      int bg = tid >> 4;
      const float invn = 1.f / 131072.f;
      float mean = s * invn;
      float var = ss * invn - mean * mean;
      sm_mean[bg] = mean;
      sm_rstd[bg] = rsqrtf(var + 1e-5f);
    }
  }
  __syncthreads();
  int b = blockIdx.x >> 7;
  int n0 = (blockIdx.x & 127) << 6;
  const float* xb = x + (size_t)b * Cch * Nvox;
  for (int i = threadIdx.x; i < 128 * 64; i += 256) {
    int c = i >> 6, nl = i & 63;
    int g = c >> 4;
    float mean = sm_mean[b * 8 + g];
    float rstd = sm_rstd[b * 8 + g];
    float v = xb[(size_t)c * Nvox + n0 + nl];
    t[nl][c] = (__bf16)((v - mean) * rstd * gamma[c] + beta[c]);
  }
  __syncthreads();
  __bf16* outb = xn + (size_t)b * Nvox * Cch;
  for (int i = threadIdx.x; i < 64 * 16; i += 256) {
    int row = i >> 4, ch = (i & 15) << 3;
    *reinterpret_cast<bf16x8*>(&outb[(size_t)(n0 + row) * Cch + ch]) =
        *reinterpret_cast<const bf16x8*>(&t[row][ch]);
  }
}

// ---------------- K3: QKV GEMM (n-tile resident) ------------------------------
// 256 blocks = b(2) x n0(128). The 64n x 128c xn tile is staged ONCE in LDS
// (padded [64][136]) and all 6 o-tiles (Q lo/hi, K lo/hi, V lo/hi) computed
// against it -> xn global reads drop 6x -> 1x (24 -> 4 MB).
// q (pre-scaled by k2), k: fp8 e4m3 [b][n][c]; v: fp8 [b][c][n] with the
// n-dim permuted within each 64-block (matches attn's in-lane P order), via
// a 4KB LDS transpose tile -> coalesced 16B global stores.
__global__ __launch_bounds__(256) void qkv_k(const __bf16* __restrict__ xn,
                                             const __bf16* __restrict__ wq,
                                             const float* __restrict__ b_qkv,
                                             unsigned char* __restrict__ q8,
                                             unsigned char* __restrict__ k8,
                                             unsigned char* __restrict__ v8t) {
  __shared__ __bf16 xt[64][136];         // 17.0 KB, padded rows
  __shared__ unsigned char vtl[64][64];  // 4 KB transpose tile
  int id = blockIdx.x;
  int b = id >> 7;
  int n0 = (id & 127) * 64;
  int w = threadIdx.x >> 6, l = threadIdx.x & 63;
  int lr = l & 15, lh = l >> 4;
  const float k2 = 0.08838834764831845f * 1.4426950408889634f;

  // stage xn tile: 64 rows x 128 c bf16
  const __bf16* xb = xn + ((size_t)b * Nvox + n0) * Cch;
  for (int i = threadIdx.x; i < 64 * 16; i += 256) {
    int row = i >> 4, ch = (i & 15) << 3;
    *reinterpret_cast<bf16x8*>(&xt[row][ch]) =
        *reinterpret_cast<const bf16x8*>(&xb[(size_t)row * Cch + ch]);
  }
  __syncthreads();

#pragma unroll
  for (int ot = 0; ot < 6; ++ot) {       // uniform o-tile loop
    int o0b = ot * 64;
    int ow = o0b + w * 16;
    bf16x8 a[4];
#pragma unroll
    for (int kc = 0; kc < 4; kc++)
      a[kc] = *reinterpret_cast<const bf16x8*>(
          &wq[(size_t)(ow + lr) * 128 + kc * 32 + lh * 8]);

#pragma unroll
    for (int ns = 0; ns < 4; ns++) {
      f32x4 acc = {0.f, 0.f, 0.f, 0.f};
#pragma unroll
      for (int kc = 0; kc < 4; kc++) {
        bf16x8 bf = *reinterpret_cast<const bf16x8*>(
            &xt[ns * 16 + lr][kc * 32 + lh * 8]);
        acc = MFMA16(a[kc], bf, acc);
      }
      int o0 = ow + lh * 4;
      int n = n0 + ns * 16 + lr;
      float f0 = acc[0] + b_qkv[o0 + 0];
      float f1 = acc[1] + b_qkv[o0 + 1];
      float f2 = acc[2] + b_qkv[o0 + 2];
      float f3 = acc[3] + b_qkv[o0 + 3];
      if (ot < 2) {
        *reinterpret_cast<unsigned int*>(
            q8 + ((size_t)b * Nvox + n) * 128 + o0) =
            pk4fp8(f0 * k2, f1 * k2, f2 * k2, f3 * k2);
      } else if (ot < 4) {
        *reinterpret_cast<unsigned int*>(
            k8 + ((size_t)b * Nvox + n) * 128 + (o0 - 128)) =
            pk4fp8(f0, f1, f2, f3);
      } else {
        // V: stage into LDS transpose tile with the n-permutation applied
        int crel = w * 16 + lh * 4;      // 0..63 within this 64-c tile
        int kk = ns * 16 + lr;           // n & 63
        int r4 = kk & 15;
        int hh = (r4 >> 2) & 1;
        int jj = (r4 & 3) + (((r4 >> 3) & 1) << 2);
        int m = ((kk >> 5) << 5) + (hh << 4) + (((kk >> 4) & 1) << 3) + jj;
        vtl[crel + 0][m] = fp8b(f0);
        vtl[crel + 1][m] = fp8b(f1);
        vtl[crel + 2][m] = fp8b(f2);
        vtl[crel + 3][m] = fp8b(f3);
      }
    }
    if (ot >= 4) {                       // uniform branch: V write-out
      __syncthreads();                   // vtl stores visible to all
      int cbase = (ot - 4) * 64;
      int row = threadIdx.x >> 2, seg = threadIdx.x & 3;
      *reinterpret_cast<u32x4*>(
          v8t + ((size_t)b * Cch + cbase + row) * Nvox + n0 + seg * 16) =
          *reinterpret_cast<const u32x4*>(&vtl[row][seg * 16]);
      __syncthreads();                   // reads done before ot=5 restores vtl
    }
  }
}

// ---------------- K4: flash attention v16 (the measured best: 49.4us) --------
// 512 blocks = qgrp(64) x b(2) x kq(4); bi&3 = kq. 4 warps, q=32/warp,
// KVBLK=64 dbuf 32KB, NT=32. fp8 K=64 MFMA (mx4), max-free softmax,
// in-lane P pack (v8t perm), setprio around MFMA clusters, race guard.
// Partials: bf16 O^T (po0..po3) + f32x2 ml (m=0, l). (256,2): wave state
// ~152 regs (88V+64A unified) — (256,4) would cap at 128 and spill (r16).
// Floor notes: barriers NOT the wall (r19 KVBLK=128 neutral); cross-iter
// MFMA pipelining neutral (r21); >2 waves/SIMD impossible at 152 regs.
__global__ __launch_bounds__(256, 2) void attn_k(const unsigned char* __restrict__ q,
                                                 const unsigned char* __restrict__ kk,
                                                 const unsigned char* __restrict__ vt,
                                                 __bf16* __restrict__ po0,
                                                 __bf16* __restrict__ po1,
                                                 __bf16* __restrict__ po2,
                                                 __bf16* __restrict__ po3,
                                                 f32x2* __restrict__ ml) {
  extern __shared__ char smem[];   // 32KB: buf{0,1} x [K 8K | V 8K]
  const int bi = blockIdx.x;
  const int kq = bi & 3;
  const int b = (bi >> 2) & 1;
  const int qgrp = bi >> 3;            // 0..63
  const int w = threadIdx.x >> 6;      // 0..3 = q-tile (32 q each)
  const int l = threadIdx.x & 63;
  const int l31 = l & 31, h = l >> 5;
  const int swl16 = (l31 & 15) << 4;   // read swizzle for 256B rows

  const char* kbase = (const char*)kk + ((size_t)b * 8192 + (size_t)kq * 2048) * 128;
  const char* vbase = (const char*)vt + (size_t)b * 1048576 + (size_t)kq * 2048;

  // Q B-fragments (fp8, pre-scaled by k2): col q = l31
  const unsigned char* qrow = q +
      ((size_t)b * 8192 + (size_t)qgrp * 128 + (size_t)w * 32 + l31) * 128 + h * 32;
  i32x8 qa8[2];
#pragma unroll
  for (int dc = 0; dc < 2; dc++) {
    i32x4 q0 = *reinterpret_cast<const i32x4*>(qrow + dc * 64);
    i32x4 q1 = *reinterpret_cast<const i32x4*>(qrow + dc * 64 + 16);
    qa8[dc] = __builtin_shufflevector(q0, q1, 0, 1, 2, 3, 4, 5, 6, 7);
  }

  f32x16 O[4];
#pragma unroll
  for (int cb = 0; cb < 4; cb++)
#pragma unroll
    for (int r = 0; r < 16; r++) O[cb][r] = 0.f;
  float s0 = 0.f, s1 = 0.f, s2 = 0.f, s3 = 0.f;  // persistent P-sum partials

  // stage one 64-row K/V fp8 tile pair (16KB): warps 0-1 K, 2-3 V; 4KB each.
  auto stage = [&](int t, int bs) {
    if (w < 2) {
      const char* kt = kbase + (size_t)t * 64 * 128;   // K rows 128B (fp8)
      char* dst = smem + bs * 16384;
#pragma unroll
      for (int it = 0; it < 4; ++it) {
        int ob = (w * 4 + it) * 1024;
        int o = ob + l * 16;
        int row = o >> 8;
        int lcol = (o & 255) ^ ((row & 15) << 4);
        int ksel = lcol >> 7, c = lcol & 127;
        GLL(kt + (size_t)(ksel * 32 + row) * 128 + c, dst + ob);
      }
    } else {
      const char* vtile = vbase + (size_t)t * 64;      // V^T c-rows 8192B (fp8)
      char* dst = smem + bs * 16384 + 8192;
#pragma unroll
      for (int it = 0; it < 4; ++it) {
        int ob = ((w - 2) * 4 + it) * 1024;
        int o = ob + l * 16;
        int row = o >> 8;
        int lcol = (o & 255) ^ ((row & 15) << 4);
        int cs = lcol >> 6, k16 = lcol & 63;
        GLL(vtile + (size_t)(cs * 32 + row) * 8192 + k16, dst + ob);
      }
    }
  };

  stage(0, 0);
  int cur = 0;
  const int NT = 32;

  for (int t = 0; t < NT; ++t) {
    // explicit drain: this wave's DMA completes before the barrier
    asm volatile("s_waitcnt vmcnt(0) lgkmcnt(0)" ::: "memory");
    __builtin_amdgcn_sched_barrier(0);
    __syncthreads();                   // buf[cur] staged for ALL waves
    if (t + 1 < NT) stage(t + 1, cur ^ 1);

    const char* Kb = smem + cur * 16384;
    const char* Vb = Kb + 8192;

    // ---- QK^T (swapped): St[ks], rows=k (ks*32+l31), cols=q (l31) ---------
    f32x16 St[2];
#pragma unroll
    for (int ks = 0; ks < 2; ks++)
#pragma unroll
      for (int r = 0; r < 16; r++) St[ks][r] = 0.f;
    __builtin_amdgcn_s_setprio(1);
#pragma unroll
    for (int ks = 0; ks < 2; ks++) {
#pragma unroll
      for (int dc = 0; dc < 2; dc++) {
        int base = ks * 128 + dc * 64 + h * 32;
        i32x4 k0 = *reinterpret_cast<const i32x4*>(
            Kb + (size_t)l31 * 256 + (base ^ swl16));
        i32x4 k1 = *reinterpret_cast<const i32x4*>(
            Kb + (size_t)l31 * 256 + ((base + 16) ^ swl16));
        St[ks] = mx4(__builtin_shufflevector(k0, k1, 0, 1, 2, 3, 4, 5, 6, 7),
                     qa8[dc], St[ks]);
      }
    }
    __builtin_amdgcn_s_setprio(0);

    // ---- max-free softmax: P = exp2(St) directly, accumulate partial sums -
#pragma unroll
    for (int ks = 0; ks < 2; ks++)
#pragma unroll
      for (int r = 0; r < 16; r++)
        St[ks][r] = __builtin_amdgcn_exp2f(St[ks][r]);
#pragma unroll
    for (int ks = 0; ks < 2; ks++)
#pragma unroll
      for (int r = 0; r < 16; r += 4) {
        s0 += St[ks][r + 0]; s1 += St[ks][r + 1];
        s2 += St[ks][r + 2]; s3 += St[ks][r + 3];
      }

    // ---- pack P to fp8 B-operand (in-lane; v8t perm matches this order) ---
    i32x8 pb;
#pragma unroll
    for (int ks = 0; ks < 2; ks++) {
      pb[ks * 4 + 0] = (int)pk4fp8(St[ks][0],  St[ks][1],  St[ks][2],  St[ks][3]);
      pb[ks * 4 + 1] = (int)pk4fp8(St[ks][4],  St[ks][5],  St[ks][6],  St[ks][7]);
      pb[ks * 4 + 2] = (int)pk4fp8(St[ks][8],  St[ks][9],  St[ks][10], St[ks][11]);
      pb[ks * 4 + 3] = (int)pk4fp8(St[ks][12], St[ks][13], St[ks][14], St[ks][15]);
    }

    // ---- PV: O^T[c][q] += V-frag x P-frag ----------------------------------
    __builtin_amdgcn_s_setprio(1);
#pragma unroll
    for (int cb = 0; cb < 4; cb++) {
      int vb0 = cb * 64 + h * 16;
      i32x4 v0 = *reinterpret_cast<const i32x4*>(
          Vb + (size_t)l31 * 256 + (vb0 ^ swl16));
      i32x4 v1 = *reinterpret_cast<const i32x4*>(
          Vb + (size_t)l31 * 256 + ((vb0 + 32) ^ swl16));
      O[cb] = mx4(__builtin_shufflevector(v0, v1, 0, 1, 2, 3, 4, 5, 6, 7),
                  pb, O[cb]);
    }
    __builtin_amdgcn_s_setprio(0);
    cur ^= 1;
  }

  // ---- epilogue: single sum reduction + write partial O^T (bf16) + (m=0,l) -
  float lsum = red32_sum((s0 + s1) + (s2 + s3));
  __bf16* po = (kq == 0) ? po0 : (kq == 1) ? po1 : (kq == 2) ? po2 : po3;
  int qg = b * 8192 + qgrp * 128 + w * 32 + l31;
#pragma unroll
  for (int cb = 0; cb < 4; cb++) {
#pragma unroll
    for (int rq = 0; rq < 4; rq++) {
      int c = cb * 32 + rq * 8 + h * 4;
      u32x2 wv;
      wv[0] = pkbf(O[cb][rq * 4 + 0], O[cb][rq * 4 + 1]);
      wv[1] = pkbf(O[cb][rq * 4 + 2], O[cb][rq * 4 + 3]);
      *reinterpret_cast<u32x2*>((char*)po + ((size_t)qg * 128 + c) * 2) = wv;
    }
  }
  if (l < 32) {
    f32x2 v; v.x = 0.f; v.y = lsum;
    ml[(size_t)kq * 16384 + qg] = v;
  }
}

// ---------------- K5: proj GEMM + fused 4-way merge + bias + residual --------
__global__ __launch_bounds__(256) void proj_k(const __bf16* __restrict__ po0,
                                              const __bf16* __restrict__ po1,
                                              const __bf16* __restrict__ po2,
                                              const __bf16* __restrict__ po3,
                                              const f32x2* __restrict__ ml,
                                              const __bf16* __restrict__ wp,
                                              const float* __restrict__ b_proj,
                                              const float* __restrict__ x,
                                              float* __restrict__ out) {
  int id = blockIdx.x;            // 2 * 2 * 128
  int b = id >> 8;
  int co0 = ((id >> 7) & 1) * 64;
  int n0 = (id & 127) * 64;
  int w = threadIdx.x >> 6, l = threadIdx.x & 63;
  int lr = l & 15, lh = l >> 4;
  int cow = co0 + w * 16;

  bf16x8 a[4];
#pragma unroll
  for (int kc = 0; kc < 4; kc++)
    a[kc] = *reinterpret_cast<const bf16x8*>(&wp[(size_t)(cow + lr) * 128 + kc * 32 + lh * 8]);

#pragma unroll
  for (int ns = 0; ns < 4; ns++) {
    int n = n0 + ns * 16 + lr;
    int qg = b * 8192 + n;
    // per-lane 4-way merge coefficients (m == 0 for all partials)
    f32x2 a0 = ml[qg], a1 = ml[16384 + qg], a2 = ml[32768 + qg], a3 = ml[49152 + qg];
    float M = fmaxf(fmaxf(a0.x, a1.x), fmaxf(a2.x, a3.x));
    float e0 = __builtin_amdgcn_exp2f(a0.x - M);
    float e1 = __builtin_amdgcn_exp2f(a1.x - M);
    float e2 = __builtin_amdgcn_exp2f(a2.x - M);
    float e3 = __builtin_amdgcn_exp2f(a3.x - M);
    float invL = 1.f / (e0 * a0.y + e1 * a1.y + e2 * a2.y + e3 * a3.y);
    float c0f = e0 * invL, c1f = e1 * invL, c2f = e2 * invL, c3f = e3 * invL;

    f32x4 acc = {0.f, 0.f, 0.f, 0.f};
#pragma unroll
    for (int kc = 0; kc < 4; kc++) {
      size_t off = (size_t)qg * 128 + kc * 32 + lh * 8;
      bf16x8 v0 = *reinterpret_cast<const bf16x8*>(&po0[off]);
      bf16x8 v1 = *reinterpret_cast<const bf16x8*>(&po1[off]);
      bf16x8 v2 = *reinterpret_cast<const bf16x8*>(&po2[off]);
      bf16x8 v3 = *reinterpret_cast<const bf16x8*>(&po3[off]);
      bf16x8 hv;
#pragma unroll
      for (int i = 0; i < 8; i++)
        hv[i] = (__bf16)(c0f * (float)v0[i] + c1f * (float)v1[i] +
                         c2f * (float)v2[i] + c3f * (float)v3[i]);
      acc = MFMA16(a[kc], hv, acc);
    }
#pragma unroll
    for (int r2 = 0; r2 < 4; r2++) {
      int co = cow + lh * 4 + r2;
      size_t idx = ((size_t)b * Cch + co) * Nvox + n;
      out[idx] = x[idx] + b_proj[co] + acc[r2];
    }
  }
}

extern "C" void kernel_launch(void* const* d_in, const int* in_sizes, int n_in,
                              void* d_out, int out_size, void* d_ws, size_t ws_size,
                              hipStream_t stream) {
  const float* x      = (const float*)d_in[0];
  const float* gamma  = (const float*)d_in[1];
  const float* beta   = (const float*)d_in[2];
  const float* w_qkv  = (const float*)d_in[3];
  const float* b_qkv  = (const float*)d_in[4];
  const float* w_proj = (const float*)d_in[5];
  const float* b_proj = (const float*)d_in[6];
  float* out = (float*)d_out;

  char* ws = (char*)d_ws;
  f32x2*  part  = (f32x2*)(ws + 256);              // 2 KB
  __bf16* wq_b  = (__bf16*)(ws + 4096);            // 98304 B
  __bf16* wp_b  = (__bf16*)(ws + 4096 + 98304);    // 32768 B
  size_t base = 135168;
  const size_t SZ = (size_t)2 * Nvox * Cch * sizeof(__bf16); // 4 MiB
  __bf16* xn  = (__bf16*)(ws + base + 0 * SZ);     // reused as po1
  unsigned char* q8  = (unsigned char*)(ws + base + 1 * SZ);  // 2 MB used
  unsigned char* k8  = (unsigned char*)(ws + base + 2 * SZ);  // 2 MB used
  unsigned char* v8t = (unsigned char*)(ws + base + 3 * SZ);  // 2 MB used
  __bf16* hw  = (__bf16*)(ws + base + 4 * SZ);     // po0
  f32x2*  ml  = (f32x2*)(ws + base + 5 * SZ);      // 512 KB
  __bf16* po2 = (__bf16*)(ws + base + 5 * SZ + 524288);
  __bf16* po3 = (__bf16*)(ws + base + 5 * SZ + 524288 + SZ);
  // total ws use: ~30 MB

  (void)hipFuncSetAttribute((const void*)attn_k,
                            hipFuncAttributeMaxDynamicSharedMemorySize, 32768);

  gn_part_k<<<256, 256, 0, stream>>>(x, part, w_qkv, w_proj, wq_b, wp_b);
  gn_apply_k<<<256, 256, 0, stream>>>(x, gamma, beta, part, xn);
  qkv_k<<<256, 256, 0, stream>>>(xn, wq_b, b_qkv, q8, k8, v8t);
  attn_k<<<512, 256, 32768, stream>>>(q8, k8, v8t, hw, xn, po2, po3, ml);
  proj_k<<<512, 256, 0, stream>>>(hw, xn, po2, po3, ml, wp_b, b_proj, x, out);
}